// Round 5
// baseline (272.931 us; speedup 1.0000x reference)
//
#include <hip/hip_runtime.h>

// PhaseCoherenceLoss: scalar reduction over (B, T=8192, 3) fp32 logits.
// For pair (t,t+1): pt=argmax[t], pt1=argmax[t+1]; if illegal[pt][pt1],
// accumulate (max logit at t+1)^2 and count. out = count>0 ? 10*loss/count : 0.
// Illegal codes pt*3+pt1 in {2,3,6,7} -> bitmask 0xCC.
//
// R1: 16K same-address atomics serialized everything (392us @ 3% BW) -> two-stage.
// R3: pcl_main ~72us, ~45% of BW floor. This round:
//   - drop the 4th (overlap) float4 load: neighbor lane already computed the
//     argmax of the next chunk's first timestep -> 2x shfl_down instead
//     (lane 63 does a rare fallback load). -25% vmem instructions.
//   - full K=8 unroll (grid = B exactly, total = B*2048 chunks = grid*256*8)
//     -> up to 24 outstanding float4 loads/thread for latency hiding.

#define TLEN      8192
#define CPR_SHIFT 11            // chunks per row = TLEN/4
#define CPR_MASK  2047u
#define NTHREADS  256
#define KCHUNK    8

__device__ __forceinline__ void argmax3(float a, float b, float c, int& bi, float& bm) {
    bm = a; bi = 0;
    if (b > bm) { bm = b; bi = 1; }     // strict >: first-max tie-break (matches argmax)
    if (c > bm) { bm = c; bi = 2; }
}

__global__ __launch_bounds__(NTHREADS) void pcl_main(const float* __restrict__ x,
                                                     float* __restrict__ part_loss,
                                                     unsigned int* __restrict__ part_cnt) {
    const unsigned int gsz = gridDim.x * NTHREADS;
    const unsigned int gid = blockIdx.x * NTHREADS + threadIdx.x;
    const int lane = threadIdx.x & 63;

    float loss = 0.0f;
    unsigned int cnt = 0;

    #pragma unroll
    for (int j = 0; j < KCHUNK; ++j) {
        unsigned int c   = gid + (unsigned int)j * gsz;   // all lanes in-bounds by construction
        unsigned int row = c >> CPR_SHIFT;
        unsigned int s4  = c & CPR_MASK;
        const float4* p = (const float4*)(x + ((size_t)row * TLEN + (s4 << 2)) * 3);

        float4 f0 = p[0];
        float4 f1 = p[1];
        float4 f2 = p[2];

        float v[4][3] = {
            {f0.x, f0.y, f0.z},
            {f0.w, f1.x, f1.y},
            {f1.z, f1.w, f2.x},
            {f2.y, f2.z, f2.w}
        };

        int   idx[4];
        float mx[4];
        #pragma unroll
        for (int k = 0; k < 4; ++k) argmax3(v[k][0], v[k][1], v[k][2], idx[k], mx[k]);

        // 5th timestep (next chunk's t0): neighbor lane's idx[0]/mx[0].
        int   nidx = __shfl_down(idx[0], 1, 64);
        float nmx  = __shfl_down(mx[0], 1, 64);
        if (lane == 63 && s4 != CPR_MASK) {
            float4 f3 = p[3];                              // rare fallback (1/64 lanes)
            argmax3(f3.x, f3.y, f3.z, nidx, nmx);
        }

        #pragma unroll
        for (int k = 0; k < 3; ++k) {
            int code = idx[k] * 3 + idx[k + 1];
            if ((0xCC >> code) & 1) { loss = fmaf(mx[k + 1], mx[k + 1], loss); cnt++; }
        }
        if (s4 != CPR_MASK) {                              // pair (t0+3, t0+4) crosses chunks
            int code = idx[3] * 3 + nidx;
            if ((0xCC >> code) & 1) { loss = fmaf(nmx, nmx, loss); cnt++; }
        }
    }

    // wave-64 reduce
    #pragma unroll
    for (int off = 32; off > 0; off >>= 1) {
        loss += __shfl_down(loss, off, 64);
        cnt  += __shfl_down(cnt,  off, 64);
    }

    __shared__ float        sl[4];
    __shared__ unsigned int sc[4];
    int wid = threadIdx.x >> 6;
    if (lane == 0) { sl[wid] = loss; sc[wid] = cnt; }
    __syncthreads();

    if (threadIdx.x == 0) {
        part_loss[blockIdx.x] = sl[0] + sl[1] + sl[2] + sl[3];
        part_cnt[blockIdx.x]  = sc[0] + sc[1] + sc[2] + sc[3];
    }
}

__global__ __launch_bounds__(NTHREADS) void pcl_final(const float* __restrict__ part_loss,
                                                      const unsigned int* __restrict__ part_cnt,
                                                      float* __restrict__ out, int npart) {
    double L = 0.0;
    unsigned int C = 0;
    for (int i = threadIdx.x; i < npart; i += NTHREADS) {
        L += (double)part_loss[i];
        C += part_cnt[i];
    }
    #pragma unroll
    for (int off = 32; off > 0; off >>= 1) {
        L += __shfl_down(L, off, 64);
        C += __shfl_down(C, off, 64);
    }
    __shared__ double       sl[4];
    __shared__ unsigned int sc[4];
    int lane = threadIdx.x & 63;
    int wid  = threadIdx.x >> 6;
    if (lane == 0) { sl[wid] = L; sc[wid] = C; }
    __syncthreads();
    if (threadIdx.x == 0) {
        double       Lt = sl[0] + sl[1] + sl[2] + sl[3];
        unsigned int Ct = sc[0] + sc[1] + sc[2] + sc[3];
        out[0] = (Ct > 0u) ? (float)(10.0 * Lt / (double)Ct) : 0.0f;
    }
}

extern "C" void kernel_launch(void* const* d_in, const int* in_sizes, int n_in,
                              void* d_out, int out_size, void* d_ws, size_t ws_size,
                              hipStream_t stream) {
    const float* x = (const float*)d_in[0];
    const int B = in_sizes[0] / (3 * TLEN);               // 2048 in this bench

    // total chunks = B*2048 = B * NTHREADS * KCHUNK / 256... grid = B exactly:
    // grid*NTHREADS*KCHUNK = B*256*8 = B*2048 = total. Every thread owns exactly
    // KCHUNK chunks -> no bounds checks, shfl always has all lanes active.
    const int grid = B;

    float*        part_loss = (float*)d_ws;
    unsigned int* part_cnt  = (unsigned int*)((char*)d_ws + (size_t)grid * sizeof(float));

    // All partial slots written unconditionally each call -> no memset needed
    // despite the 0xAA ws re-poison.
    pcl_main<<<grid, NTHREADS, 0, stream>>>(x, part_loss, part_cnt);
    pcl_final<<<1, NTHREADS, 0, stream>>>(part_loss, part_cnt, (float*)d_out, grid);
}